// Round 1
// baseline (233.382 us; speedup 1.0000x reference)
//
#include <hip/hip_runtime.h>
#include <hip/hip_bf16.h>

#define NROWS 16384
#define DIM 128

typedef __attribute__((ext_vector_type(8))) __bf16 bf16x8;
typedef __attribute__((ext_vector_type(4))) float f32x4;
typedef unsigned int u32;
typedef unsigned short u16;

#if __has_builtin(__builtin_amdgcn_exp2f)
#define EXP2F(x) __builtin_amdgcn_exp2f(x)
#else
#define EXP2F(x) exp2f(x)
#endif

// K1 = log2(e)/tau ; score = cos/tau ; exp(score - 1/tau) = exp2(cos*K1 - K1)
#define K1_CONST 20.6099273650808706f

__device__ __forceinline__ u16 f2bf(float x) {
  __hip_bfloat16 h = __float2bfloat16(x);
  return *reinterpret_cast<u16*>(&h);
}

__device__ __forceinline__ void gload_lds16(const void* g, void* l) {
  __builtin_amdgcn_global_load_lds(
      (const __attribute__((address_space(1))) u32*)g,
      (__attribute__((address_space(3))) u32*)l, 16, 0, 0);
}

// ---------------- Kernel A: row L2-normalize -> bf16, pos_sim (fp32) -------
__global__ __launch_bounds__(256) void nrm_kernel(
    const float* __restrict__ z1, const float* __restrict__ z2,
    u16* __restrict__ z1n, u16* __restrict__ z2n, float* __restrict__ pos_sim)
{
  const int tid  = threadIdx.x;
  const int lane = tid & 63, wid = tid >> 6;
  const int row  = blockIdx.x * 4 + wid;
  const float2 a = *(const float2*)(z1 + (size_t)row * DIM + lane * 2);
  const float2 b = *(const float2*)(z2 + (size_t)row * DIM + lane * 2);
  float ss1 = a.x * a.x + a.y * a.y;
  float ss2 = b.x * b.x + b.y * b.y;
  float dd  = a.x * b.x + a.y * b.y;
#pragma unroll
  for (int d = 1; d < 64; d <<= 1) {
    ss1 += __shfl_xor(ss1, d);
    ss2 += __shfl_xor(ss2, d);
    dd  += __shfl_xor(dd,  d);
  }
  const float inv1 = 1.0f / fmaxf(sqrtf(ss1), 1e-12f);
  const float inv2 = 1.0f / fmaxf(sqrtf(ss2), 1e-12f);
  u32 p1 = (u32)f2bf(a.x * inv1) | ((u32)f2bf(a.y * inv1) << 16);
  u32 p2 = (u32)f2bf(b.x * inv2) | ((u32)f2bf(b.y * inv2) << 16);
  ((u32*)z1n)[(size_t)row * (DIM / 2) + lane] = p1;
  ((u32*)z2n)[(size_t)row * (DIM / 2) + lane] = p2;
  if (lane == 0) pos_sim[row] = dd * inv1 * inv2 * (1.0f / 0.07f);
}

// ---------------- Kernel B: fused GEMM + fixed-max sum-exp ------------------
// grid = 512 : rb = bx>>2 (128 q-rows each), ch = bx&3 (8192 concat-cols each)
// concat columns: [0,16384) -> z2n rows ; [16384,32768) -> z1n rows
__global__ __launch_bounds__(512) void lse_kernel(
    const u16* __restrict__ z1n, const u16* __restrict__ z2n,
    float* __restrict__ lparts)
{
  __shared__ __attribute__((aligned(16))) char smem[32768]; // 2 x 64x128 bf16
  const int tid    = threadIdx.x;
  const int lane   = tid & 63, wid = tid >> 6;
  const int rb     = blockIdx.x >> 2, ch = blockIdx.x & 3;
  const int lane15 = lane & 15, laneHi = lane >> 4, lane7 = lane & 7;
  const int qrow   = rb * 128 + wid * 16 + lane15;

  // Q fragments (B-operand): lane -> q-row = lane&15, k = 32*ks + 8*(lane>>4)+i
  bf16x8 qf[4];
#pragma unroll
  for (int ks = 0; ks < 4; ++ks)
    qf[ks] = *(const bf16x8*)(z1n + (size_t)qrow * DIM + ks * 32 + laneHi * 8);

  // staging: LDS linear, global source pre-swizzled (chunk ^= row&7)
  const int gchunk = (tid & 15) ^ ((tid >> 4) & 7);
  const int soff   = ((tid >> 4) << 8) + (gchunk << 4); // bytes within tile
  char* const lds_wave = smem + (wid << 10);

  float lacc[4] = {0.f, 0.f, 0.f, 0.f};
  const int cb0 = ch * 8192;

  auto stage = [&](int t, int cur) {
    const int cb = cb0 + t * 64;
    const u16* zt = (cb < NROWS) ? (z2n + (size_t)cb * DIM)
                                 : (z1n + (size_t)(cb - NROWS) * DIM);
    const char* src = (const char*)zt + soff;
    char* dst = lds_wave + cur * 16384;
    gload_lds16(src, dst);
    gload_lds16(src + 8192, dst + 8192);
  };

  auto compute = [&](int cur, int diag_k) {
    const char* buf = smem + cur * 16384;
#pragma unroll
    for (int kb = 0; kb < 4; ++kb) {
      const int rowb = (kb * 16 + lane15) * 256;
      bf16x8 af[4];
#pragma unroll
      for (int ks = 0; ks < 4; ++ks) {
        const int off = rowb + ((((ks << 2) + laneHi) ^ lane7) << 4);
        af[ks] = *(const bf16x8*)(buf + off);
      }
      f32x4 acc = {0.f, 0.f, 0.f, 0.f};
#pragma unroll
      for (int ks = 0; ks < 4; ++ks)
        acc = __builtin_amdgcn_mfma_f32_16x16x32_bf16(af[ks], qf[ks], acc, 0, 0, 0);
      // acc[j]: k_local = kb*16 + laneHi*4 + j, q-row = lane15
      if (diag_k < 0) { // wave-uniform branch
#pragma unroll
        for (int j = 0; j < 4; ++j)
          lacc[j] += EXP2F(fmaf(acc[j], K1_CONST, -K1_CONST));
      } else {
#pragma unroll
        for (int j = 0; j < 4; ++j) {
          float v = EXP2F(fmaf(acc[j], K1_CONST, -K1_CONST));
          const int kl = kb * 16 + laneHi * 4 + j;
          if (kl == diag_k) v = 0.0f;
          lacc[j] += v;
        }
      }
    }
  };

  stage(0, 0);
  __syncthreads();
  int cur = 0;
#pragma unroll 1
  for (int t = 0; t < 128; ++t) {
    if (t + 1 < 128) stage(t + 1, cur ^ 1);
    const int cb = cb0 + t * 64;
    const int dbase = cb - NROWS; // z1-col base (valid when cb>=NROWS)
    // wave-uniform: does this tile hold this wave's diagonal?
    const bool has_diag =
        (cb >= NROWS) && ((u32)(rb * 128 + wid * 16 - dbase) < 64u);
    const int diag_k = has_diag ? (qrow - dbase) : -1;
    compute(cur, diag_k);
    __syncthreads();
    cur ^= 1;
  }

  float l = (lacc[0] + lacc[1]) + (lacc[2] + lacc[3]);
  l += __shfl_xor(l, 16);
  l += __shfl_xor(l, 32);
  if (lane < 16) lparts[(size_t)ch * NROWS + qrow] = l;
}

// ---------------- Kernel C: finalize --------------------------------------
__global__ __launch_bounds__(1024) void fin_kernel(
    const float* __restrict__ lparts, const float* __restrict__ pos,
    float* __restrict__ out)
{
  __shared__ float red[16];
  const int tid = threadIdx.x;
  float s = 0.f;
  for (int i = tid; i < NROWS; i += 1024) {
    float l = (lparts[i] + lparts[NROWS + i]) +
              (lparts[2 * NROWS + i] + lparts[3 * NROWS + i]);
    s += (1.0f / 0.07f) + logf(l) - pos[i];
  }
#pragma unroll
  for (int d = 1; d < 64; d <<= 1) s += __shfl_xor(s, d);
  if ((tid & 63) == 0) red[tid >> 6] = s;
  __syncthreads();
  if (tid == 0) {
    float t = 0.f;
#pragma unroll
    for (int w = 0; w < 16; ++w) t += red[w];
    out[0] = t / (float)NROWS;
  }
}

extern "C" void kernel_launch(void* const* d_in, const int* in_sizes, int n_in,
                              void* d_out, int out_size, void* d_ws, size_t ws_size,
                              hipStream_t stream) {
  const float* z1 = (const float*)d_in[0];
  const float* z2 = (const float*)d_in[1];
  float* out = (float*)d_out;
  char* ws = (char*)d_ws;
  u16* z1n = (u16*)ws;                                        // 4 MB
  u16* z2n = (u16*)(ws + (size_t)NROWS * DIM * 2);            // 4 MB
  float* pos = (float*)(ws + (size_t)NROWS * DIM * 4);        // 64 KB
  float* lparts = (float*)(ws + (size_t)NROWS * DIM * 4 + (size_t)NROWS * 4); // 256 KB

  hipLaunchKernelGGL(nrm_kernel, dim3(NROWS / 4), dim3(256), 0, stream,
                     z1, z2, z1n, z2n, pos);
  hipLaunchKernelGGL(lse_kernel, dim3(512), dim3(512), 0, stream,
                     z1n, z2n, lparts);
  hipLaunchKernelGGL(fin_kernel, dim3(1), dim3(1024), 0, stream,
                     lparts, pos, out);
}